// Round 3
// baseline (612.905 us; speedup 1.0000x reference)
//
#include <hip/hip_runtime.h>
#include <math.h>

#define BB 2
#define CC 192
#define NH 4
#define CH 48
#define HH 256
#define WW 256
#define NPIX (HH*WW)

typedef __attribute__((ext_vector_type(8))) short short8;   // 8 bf16 = 4 VGPR
typedef __attribute__((ext_vector_type(4))) float f4;

static __device__ __forceinline__ unsigned short f2bf(float f) {
    union { float f; unsigned int u; } c; c.f = f;
    unsigned int r = c.u + 0x7fffu + ((c.u >> 16) & 1u);
    return (unsigned short)(r >> 16);
}

template<int CTRL>
static __device__ __forceinline__ float dppmv(float v) {
    // bound_ctrl=true: out-of-range source lane -> 0 (== conv zero padding)
    return __int_as_float(__builtin_amdgcn_update_dpp(
        0, __float_as_int(v), CTRL, 0xf, 0xf, true));
}
#define WAVE_SHR1 0x138   // lane i <- lane i-1 (left neighbor)
#define WAVE_SHL1 0x130   // lane i <- lane i+1 (right neighbor)

static __device__ __forceinline__ float rdlane(float v, int l) {
    return __int_as_float(__builtin_amdgcn_readlane(__float_as_int(v), l));
}

// K1: depthwise 3x3 conv for one (b, head, y, 128-px half-row).
// Loads only row centers (3/channel) + one 6-lane halo load; x+-1 neighbors
// come from DPP wave shifts. Weights via uniform (s_load) access, no LDS.
// q,k -> LDS bf16 [type][48][128px] (72-dword stride); v -> global [n][dg] bf16.
// Then sumsq and S += q k^T via MFMA 16x16x32 (9 tiles x 4 K-steps / 4 waves).
__global__ __launch_bounds__(256, 4) void k_conv(
    const float* __restrict__ x, const float* __restrict__ wqkv,
    unsigned short* __restrict__ vws, float* __restrict__ Sws,
    float* __restrict__ sqws)
{
    __shared__ unsigned int qk32[2][CH][72];   // 27648 B (64 dw data + 8 pad)

    const int tid = threadIdx.x;
    const int hd = blockIdx.x;
    const int y  = blockIdx.y >> 1;
    const int x0 = (blockIdx.y & 1) * 128;
    const int b  = blockIdx.z;

    const int lane  = tid & 63;
    const int chalf = tid >> 7;              // channel half (0: ch 0-23, 1: 24-47)
    const int lpx   = tid & 127;             // local pixel
    const int xp    = x0 + lpx;
    const int wstart = x0 + (((tid >> 6) & 1) << 6);

    const int y0c = (y > 0) ? y-1 : 0;
    const int y2c = (y < HH-1) ? y+1 : y;
    const float m0 = (y > 0) ? 1.f : 0.f;
    const float m2 = (y < HH-1) ? 1.f : 0.f;
    const int ro0 = y0c*WW, ro1 = y*WW, ro2 = y2c*WW;

    // halo lanes 0..5: row = lane>>1 (y-1,y,y+1), side = lane&1 (left,right)
    const int hrow = lane >> 1;
    const int hside = lane & 1;
    const int hx = hside ? (wstart + 64) : (wstart - 1);
    const bool hact = (lane < 6) && (hx >= 0) && (hx < WW);
    const int hoff = ((hrow == 0) ? ro0 : ((hrow == 1) ? ro1 : ro2)) + hx;
    const float hmask = (hrow == 0) ? m0 : ((hrow == 2) ? m2 : 1.f);
    const bool is0  = (lane == 0);
    const bool is63 = (lane == 63);

    unsigned int vpack[12];

    #pragma unroll
    for (int type = 0; type < 3; ++type) {
        #pragma unroll
        for (int gg = 0; gg < 8; ++gg) {
            const int g  = chalf*8 + gg;
            const int ic = type*64 + hd*16 + g;
            const float* xch = x + ((size_t)(b*CC + ic))*NPIX;      // uniform
            const float* wp9 = wqkv + ((size_t)(type*CC + hd*CH + 3*g))*9; // uniform -> s_load

            float v0 = xch[ro0 + xp] * m0;
            float v1 = xch[ro1 + xp];
            float v2 = xch[ro2 + xp] * m2;
            float hv = 0.f;
            if (hact) hv = xch[hoff];
            hv *= hmask;

            float l0 = dppmv<WAVE_SHR1>(v0), r0 = dppmv<WAVE_SHL1>(v0);
            float l1 = dppmv<WAVE_SHR1>(v1), r1 = dppmv<WAVE_SHL1>(v1);
            float l2 = dppmv<WAVE_SHR1>(v2), r2 = dppmv<WAVE_SHL1>(v2);
            float sL0 = rdlane(hv, 0), sR0 = rdlane(hv, 1);
            float sL1 = rdlane(hv, 2), sR1 = rdlane(hv, 3);
            float sL2 = rdlane(hv, 4), sR2 = rdlane(hv, 5);
            l0 = is0 ? sL0 : l0;  r0 = is63 ? sR0 : r0;
            l1 = is0 ? sL1 : l1;  r1 = is63 ? sR1 : r1;
            l2 = is0 ? sL2 : l2;  r2 = is63 ? sR2 : r2;

            #pragma unroll
            for (int rr = 0; rr < 3; ++rr) {
                const float* w = wp9 + rr*9;
                float val = l0*w[0] + v0*w[1] + r0*w[2]
                          + l1*w[3] + v1*w[4] + r1*w[5]
                          + l2*w[6] + v2*w[7] + r2*w[8];
                if (type == 2) {
                    const int cll = 3*gg + rr;            // 0..23
                    unsigned int u = f2bf(val);
                    if (cll & 1) vpack[cll >> 1] |= (u << 16);
                    else         vpack[cll >> 1]  = u;
                } else {
                    const int cl = 3*g + rr;              // 0..47
                    ((unsigned short*)&qk32[type][cl][0])[lpx] = f2bf(val);
                }
            }
        }
    }

    // v store: [b][n][dg] bf16, 3 x dwordx4 per thread (16B aligned)
    {
        unsigned short* vp = vws + ((size_t)b*NPIX + (size_t)y*WW + xp)*CC
                             + hd*CH + chalf*24;
        #pragma unroll
        for (int st = 0; st < 3; ++st) {
            uint4 u; u.x = vpack[st*4+0]; u.y = vpack[st*4+1];
                     u.z = vpack[st*4+2]; u.w = vpack[st*4+3];
            *(uint4*)(vp + st*8) = u;
        }
    }
    __syncthreads();

    // per-channel sum of squares over this 128-px segment
    if (tid < 2*CH) {
        const int which = tid / CH;
        const int cl = tid - which*CH;
        const uint4* row = (const uint4*)&qk32[which][cl][0];
        float ssum = 0.f;
        #pragma unroll
        for (int j = 0; j < 16; ++j) {
            uint4 u = row[j];
            #pragma unroll
            for (int q4 = 0; q4 < 4; ++q4) {
                unsigned int w = (&u.x)[q4];
                float lo = __uint_as_float(w << 16);
                float hi = __uint_as_float(w & 0xffff0000u);
                ssum = fmaf(lo, lo, ssum);
                ssum = fmaf(hi, hi, ssum);
            }
        }
        atomicAdd(&sqws[((b*NH + hd)*2 + which)*CH + cl], ssum);
    }

    // S = q k^T via MFMA over this 128-px segment (K = 4 x 32)
    {
        const int wv = tid >> 6;
        const int m = lane & 15, quad = lane >> 4;
        for (int p = wv; p < 9; p += 4) {
            const int ct = p / 3, dt = p - ct*3;
            f4 acc = {0.f, 0.f, 0.f, 0.f};
            const char* qb = (const char*)&qk32[0][ct*16 + m][0] + quad*16;
            const char* kb = (const char*)&qk32[1][dt*16 + m][0] + quad*16;
            #pragma unroll
            for (int ks = 0; ks < 4; ++ks) {
                short8 afr = *(const short8*)(qb + ks*64);
                short8 bfr = *(const short8*)(kb + ks*64);
                acc = __builtin_amdgcn_mfma_f32_16x16x32_bf16(afr, bfr, acc, 0, 0, 0);
            }
            const int c0 = ct*16 + quad*4, d = dt*16 + m;
            float* Sp = Sws + ((size_t)(b*NH + hd)*CH + c0)*CH + d;
            #pragma unroll
            for (int r = 0; r < 4; ++r) atomicAdd(Sp + r*CH, acc[r]);
        }
    }
}

// K2: one block per (b,head): norms -> logits -> softmax -> W2 = wproj*attn,
// exported bf16 in [o][dg] (A-operand-ready) layout.
__global__ __launch_bounds__(256) void k_attn(
    const float* __restrict__ Sws, const float* __restrict__ sqws,
    const float* __restrict__ temp, const float* __restrict__ wproj,
    unsigned short* __restrict__ W2bf)
{
    __shared__ float att[CH][CH+1];
    __shared__ float wp[CC][CH+1];
    __shared__ float nrm[2][CH];

    const int tid = threadIdx.x;
    const int b  = blockIdx.x >> 2;
    const int hd = blockIdx.x & 3;

    if (tid < 2*CH) {
        int which = tid / CH, cl = tid - which*CH;
        nrm[which][cl] = fmaxf(sqrtf(sqws[((b*NH + hd)*2 + which)*CH + cl]), 1e-12f);
    }
    __syncthreads();

    const float tscale = temp[hd];
    for (int m = tid; m < CH*CH; m += 256) {
        int c = m / CH, d = m - c*CH;
        att[c][d] = Sws[((size_t)(b*NH + hd)*CH + c)*CH + d] * tscale
                    / (nrm[0][c] * nrm[1][d]);
    }
    __syncthreads();

    if (tid < CH) {
        float mx = -1e30f;
        for (int d = 0; d < CH; ++d) mx = fmaxf(mx, att[tid][d]);
        float sm = 0.f;
        for (int d = 0; d < CH; ++d) { float e = expf(att[tid][d] - mx); att[tid][d] = e; sm += e; }
        float inv = 1.f / sm;
        for (int d = 0; d < CH; ++d) att[tid][d] *= inv;
    }

    for (int m = tid; m < CC*CH; m += 256) {
        int o = m / CH, il = m - o*CH;
        wp[o][il] = wproj[o*CC + hd*CH + il];
    }
    __syncthreads();

    const int o0  = (tid & 31) * 6;
    const int dl0 = (tid >> 5) * 6;
    float a[6][6];
    #pragma unroll
    for (int i = 0; i < 6; ++i)
        #pragma unroll
        for (int j = 0; j < 6; ++j) a[i][j] = 0.f;
    for (int il = 0; il < CH; ++il) {
        float wv[6], av[6];
        #pragma unroll
        for (int i = 0; i < 6; ++i) wv[i] = wp[o0+i][il];
        #pragma unroll
        for (int j = 0; j < 6; ++j) av[j] = att[il][dl0+j];
        #pragma unroll
        for (int i = 0; i < 6; ++i)
            #pragma unroll
            for (int j = 0; j < 6; ++j)
                a[i][j] = fmaf(wv[i], av[j], a[i][j]);
    }
    #pragma unroll
    for (int i = 0; i < 6; ++i)
        #pragma unroll
        for (int j = 0; j < 6; ++j)
            W2bf[((size_t)b*CC + o0 + i)*CC + hd*CH + dl0 + j] = f2bf(a[i][j]);
}

// K3: out[b][o][n] = sum_dg W2[o][dg] v[n][dg]  — MFMA GEMM, no LDS.
// Block: M=192 x N=128, 4 waves 2x2. A-frags direct from global (W2 is 73KB,
// L2-hot); B-frags 16B loads from v at 64B granularity.
__global__ __launch_bounds__(256, 3) void k_out(
    const unsigned short* __restrict__ vws, const unsigned short* __restrict__ W2bf,
    float* __restrict__ out)
{
    const int tid = threadIdx.x;
    const int b  = blockIdx.y;
    const int n0 = blockIdx.x * 128;

    const int lane = tid & 63;
    const int wv = tid >> 6;
    const int m0  = (wv & 1) * 96;
    const int nn0 = (wv >> 1) * 64;
    const int m = lane & 15, quad = lane >> 4;

    f4 acc[6][4];
    #pragma unroll
    for (int mt = 0; mt < 6; ++mt)
        #pragma unroll
        for (int nt = 0; nt < 4; ++nt) acc[mt][nt] = (f4){0.f, 0.f, 0.f, 0.f};

    const unsigned short* vb = vws + ((size_t)b*NPIX + n0 + nn0 + m)*CC + quad*8;
    const unsigned short* ab = W2bf + ((size_t)b*CC + m0 + m)*CC + quad*8;

    #pragma unroll
    for (int ks = 0; ks < 6; ++ks) {
        short8 bfr[4];
        #pragma unroll
        for (int nt = 0; nt < 4; ++nt)
            bfr[nt] = *(const short8*)(vb + (size_t)(nt*16)*CC + ks*32);
        short8 afr[6];
        #pragma unroll
        for (int mt = 0; mt < 6; ++mt)
            afr[mt] = *(const short8*)(ab + (size_t)(mt*16)*CC + ks*32);
        #pragma unroll
        for (int mt = 0; mt < 6; ++mt)
            #pragma unroll
            for (int nt = 0; nt < 4; ++nt)
                acc[mt][nt] = __builtin_amdgcn_mfma_f32_16x16x32_bf16(afr[mt], bfr[nt], acc[mt][nt], 0, 0, 0);
    }

    #pragma unroll
    for (int mt = 0; mt < 6; ++mt) {
        const int o = m0 + mt*16 + quad*4;
        #pragma unroll
        for (int nt = 0; nt < 4; ++nt) {
            const int px = n0 + nn0 + nt*16 + m;
            float* op = out + ((size_t)(b*CC + o))*NPIX + px;
            #pragma unroll
            for (int r = 0; r < 4; ++r) op[(size_t)r*NPIX] = acc[mt][nt][r];
        }
    }
}

extern "C" void kernel_launch(void* const* d_in, const int* in_sizes, int n_in,
                              void* d_out, int out_size, void* d_ws, size_t ws_size,
                              hipStream_t stream)
{
    const float* x     = (const float*)d_in[0];
    const float* wqkv  = (const float*)d_in[1];
    const float* temp  = (const float*)d_in[2];
    const float* wproj = (const float*)d_in[3];
    float* out = (float*)d_out;
    (void)in_sizes; (void)n_in; (void)out_size; (void)ws_size;

    unsigned short* vws = (unsigned short*)d_ws;                 // [b][n][dg] bf16
    const size_t VBYTES = (size_t)BB*CC*NPIX*sizeof(unsigned short);
    float* Sws  = (float*)((char*)d_ws + VBYTES);                // 18432 f
    float* sqws = Sws + (size_t)BB*NH*CH*CH;                     // 768 f
    unsigned short* W2bf = (unsigned short*)(sqws + (size_t)BB*NH*2*CH); // 73728 u16

    hipMemsetAsync(Sws, 0, (size_t)(BB*NH*CH*CH + BB*NH*2*CH)*sizeof(float), stream);
    k_conv<<<dim3(NH, 2*HH, BB), 256, 0, stream>>>(x, wqkv, vws, Sws, sqws);
    k_attn<<<dim3(BB*NH), 256, 0, stream>>>(Sws, sqws, temp, wproj, W2bf);
    k_out<<<dim3(NPIX/128, BB), 256, 0, stream>>>(vws, W2bf, out);
}